// Round 2
// 88.850 us; speedup vs baseline: 1.0522x; 1.0522x over previous
//
#include <hip/hip_runtime.h>
#include <hip/hip_bf16.h>

#define N 4096
#define D 512
#define MARGIN 0.5f
#define BETA 10.0f

typedef __attribute__((ext_vector_type(8))) short short8;
typedef __attribute__((ext_vector_type(4))) float floatx4;

__device__ inline unsigned short f2bf(float f) {
    unsigned u = __float_as_uint(f);
    u += 0x7fffu + ((u >> 16) & 1u);   // round-to-nearest-even
    return (unsigned short)(u >> 16);
}

// ---- Kernel 1: f32 -> bf16 convert + zero the accumulator buffers ----
__global__ __launch_bounds__(256) void convert_bf16_kernel(
        const float4* __restrict__ in, ushort4* __restrict__ out,
        float* __restrict__ sums /* 2*N floats to zero */) {
    int idx = blockIdx.x * 256 + threadIdx.x;
    if (idx < 2 * N) sums[idx] = 0.f;
    float4 v = in[idx];
    ushort4 o;
    o.x = f2bf(v.x); o.y = f2bf(v.y); o.z = f2bf(v.z); o.w = f2bf(v.w);
    out[idx] = o;
}

// ---- Kernel 2: fused sim-GEMM + masked exp sums, UPPER-TRIANGLE only ----
// sim = E.E^T is symmetric: block t decodes to tile (bi<=bj) and credits
// rows ibase.. (sum over cols) AND rows jbase.. (sum over rows) with the
// same exp values. 528 blocks instead of 1024.
//
// R1 change: double-buffered LDS + 2-phase prefetch schedule.
// Old loop: barrier; issue loads; barrier (drains vmcnt BEFORE MFMA) -> a
// full L2-latency stall per K-step, x16, with only ~2 blocks/CU to mask it.
// New loop: STAGE(next) issued first, then ds_read+MFMA on current buffer,
// then ONE vmcnt(0)+barrier per K-step. Load latency hides under the
// 16-MFMA cluster; barrier count halves (32 -> 16).
__global__ __launch_bounds__(256, 4) void ms_loss_gemm(
        const unsigned short* __restrict__ Ebf,
        const int* __restrict__ labels,
        float* __restrict__ pos_sum,
        float* __restrict__ neg_sum) {
    __shared__ unsigned short Atile[2][128 * 32];   // 2 x 8 KB
    __shared__ unsigned short Btile[2][128 * 32];   // 2 x 8 KB
    __shared__ int rlab[128];
    __shared__ int clab[128];

    // decode linear block id -> upper-triangle tile (bi, bj), bi <= bj
    int t = blockIdx.x;
    int bi = 0;
    while (t >= (32 - bi)) { t -= (32 - bi); ++bi; }
    const int bj = bi + t;
    const bool diag = (bi == bj);

    const int tid  = threadIdx.x;
    const int wave = tid >> 6;
    const int lane = tid & 63;
    const int quad = lane >> 4;      // 0..3
    const int lcol = lane & 15;      // 0..15
    const int wrow = wave >> 1;      // 0..1
    const int wcol = wave & 1;       // 0..1
    const int ibase = bi * 128;
    const int jbase = bj * 128;

    if (tid < 128)       rlab[tid]       = labels[ibase + tid];
    else                 clab[tid - 128] = labels[jbase + tid - 128];

    floatx4 acc[4][4];
#pragma unroll
    for (int mt = 0; mt < 4; ++mt)
#pragma unroll
        for (int nt = 0; nt < 4; ++nt)
            acc[mt][nt] = (floatx4){0.f, 0.f, 0.f, 0.f};

    const char* Eb = (const char*)Ebf;           // row stride = 1024 B
    char* Ab = (char*)Atile;                      // buffer stride 8192 B
    char* Bb = (char*)Btile;
    const int srow = lane >> 2;                       // 0..15
    const int sckb = ((lane & 3) ^ ((lane >> 3) & 3)) * 16;  // swizzled chunk
    const int rdsw = ((lcol >> 1) & 3);               // read-side XOR term

    // Staging: byte-identical swizzle to the verified kernel, plus a
    // double-buffer index. LDS dest stays wave-linear (HW requirement);
    // swizzle is applied on the GLOBAL source address.
#define STAGE(BUF, KT)                                                         \
    do {                                                                       \
        const int kb_ = (KT) * 64;                                             \
        _Pragma("unroll")                                                      \
        for (int it_ = 0; it_ < 2; ++it_) {                                    \
            int r_    = wave * 16 + it_ * 64 + srow;                           \
            int ldso_ = (BUF) * 8192 + wave * 1024 + it_ * 4096 + lane * 16;   \
            const char* ga_ = Eb + (size_t)(ibase + r_) * (D * 2) + kb_ + sckb;\
            __builtin_amdgcn_global_load_lds(                                  \
                (const __attribute__((address_space(1))) void*)ga_,            \
                (__attribute__((address_space(3))) void*)(Ab + ldso_), 16, 0, 0);\
            if (!diag) {                                                       \
                const char* gb_ = Eb + (size_t)(jbase + r_) * (D * 2) + kb_ + sckb;\
                __builtin_amdgcn_global_load_lds(                              \
                    (const __attribute__((address_space(1))) void*)gb_,        \
                    (__attribute__((address_space(3))) void*)(Bb + ldso_), 16, 0, 0);\
            }                                                                  \
        }                                                                      \
    } while (0)

    STAGE(0, 0);
    __syncthreads();   // drains vmcnt(0): buffer 0 ready

#pragma unroll 2
    for (int kt = 0; kt < D / 32; ++kt) {
        const int cur = kt & 1;
        if (kt < D / 32 - 1) STAGE(cur ^ 1, kt + 1);   // prefetch next K-slab

        const char* Ar = Ab + cur * 8192;
        const char* Br = diag ? Ar : (Bb + cur * 8192);

        short8 a[4], b[4];
        const int rchunk = (quad ^ rdsw) * 16;
#pragma unroll
        for (int mt = 0; mt < 4; ++mt) {
            int r = wrow * 64 + mt * 16 + lcol;
            a[mt] = *(const short8*)(Ar + r * 64 + rchunk);
        }
#pragma unroll
        for (int nt = 0; nt < 4; ++nt) {
            int c = wcol * 64 + nt * 16 + lcol;
            b[nt] = *(const short8*)(Br + c * 64 + rchunk);
        }
#pragma unroll
        for (int mt = 0; mt < 4; ++mt)
#pragma unroll
            for (int nt = 0; nt < 4; ++nt)
                acc[mt][nt] = __builtin_amdgcn_mfma_f32_16x16x32_bf16(
                    a[mt], b[nt], acc[mt][nt], 0, 0, 0);

        // ONE barrier per K-step: drains the prefetch (vmcnt) AFTER the
        // MFMA cluster, and gates the buffer swap.
        __syncthreads();
    }
#undef STAGE

    // ---- epilogue ----
    // C layout (m89-verified): col = lane&15, row = quad*4 + reg
    int ljv[4], gjv[4];
#pragma unroll
    for (int nt = 0; nt < 4; ++nt) {
        int cl = wcol * 64 + nt * 16 + lcol;
        ljv[nt] = clab[cl];
        gjv[nt] = jbase + cl;
    }

    float colp[4] = {0.f, 0.f, 0.f, 0.f};
    float coln[4] = {0.f, 0.f, 0.f, 0.f};

#pragma unroll
    for (int mt = 0; mt < 4; ++mt) {
#pragma unroll
        for (int reg = 0; reg < 4; ++reg) {
            int rl = wrow * 64 + mt * 16 + quad * 4 + reg;
            int gi = ibase + rl;
            int li = rlab[rl];
            float p = 0.f, ng = 0.f;
#pragma unroll
            for (int nt = 0; nt < 4; ++nt) {
                float s = acc[mt][nt][reg];
                if (gi != gjv[nt]) {
                    if (li == ljv[nt]) {
                        float e = __expf(MARGIN - s);          // alpha = 1
                        p += e;  colp[nt] += e;
                    } else {
                        float e = __expf(BETA * (s - MARGIN));
                        ng += e; coln[nt] += e;
                    }
                }
            }
            // row-sum: reduce across the 16 lcol lanes (distinct cols)
            p  += __shfl_xor(p, 1);   ng += __shfl_xor(ng, 1);
            p  += __shfl_xor(p, 2);   ng += __shfl_xor(ng, 2);
            p  += __shfl_xor(p, 4);   ng += __shfl_xor(ng, 4);
            p  += __shfl_xor(p, 8);   ng += __shfl_xor(ng, 8);
            if (lcol == 0) {
                atomicAdd(&pos_sum[gi], p);
                atomicAdd(&neg_sum[gi], ng);
            }
        }
    }

    // col-sum (mirror credit), off-diagonal blocks only:
    // reduce across quads (xor 16,32); lane's col = nt*16+lcol.
    if (!diag) {
#pragma unroll
        for (int nt = 0; nt < 4; ++nt) {
            float cp = colp[nt], cn = coln[nt];
            cp += __shfl_xor(cp, 16);  cn += __shfl_xor(cn, 16);
            cp += __shfl_xor(cp, 32);  cn += __shfl_xor(cn, 32);
            if (quad == 0) {
                int gj = gjv[nt];
                atomicAdd(&pos_sum[gj], cp);
                atomicAdd(&neg_sum[gj], cn);
            }
        }
    }
}

// ---- Kernel 3: finalize (1024 threads: one float4 per thread, no serial loop) ----
__global__ __launch_bounds__(1024) void finalize_kernel(
        const float4* __restrict__ pos4, const float4* __restrict__ neg4,
        float* __restrict__ out) {
    __shared__ float sb[16];
    __shared__ int   sc[16];
    const int tid = threadIdx.x;          // 0..1023 ; N/4 = 1024 float4s
    float4 p  = pos4[tid];
    float4 ng = neg4[tid];
    const float* pp = (const float*)&p;
    const float* nn = (const float*)&ng;
    float tot = 0.f;
    int cnt = 0;
#pragma unroll
    for (int j = 0; j < 4; ++j) {
        if (pp[j] > 0.f && nn[j] > 0.f) {
            tot += log1pf(pp[j]) + (1.0f / BETA) * log1pf(nn[j]);
            cnt += 1;
        }
    }
#pragma unroll
    for (int s = 1; s < 64; s <<= 1) {
        tot += __shfl_xor(tot, s);
        cnt += __shfl_xor(cnt, s);
    }
    if ((tid & 63) == 0) { sb[tid >> 6] = tot; sc[tid >> 6] = cnt; }
    __syncthreads();
    if (tid < 16) {
        float t2 = sb[tid];
        int   c2 = sc[tid];
#pragma unroll
        for (int s = 1; s < 16; s <<= 1) {
            t2 += __shfl_xor(t2, s);
            c2 += __shfl_xor(c2, s);
        }
        if (tid == 0) out[0] = (c2 > 0) ? t2 / (float)c2 : 0.f;
    }
}

extern "C" void kernel_launch(void* const* d_in, const int* in_sizes, int n_in,
                              void* d_out, int out_size, void* d_ws, size_t ws_size,
                              hipStream_t stream) {
    const float* emb   = (const float*)d_in[0];
    const int* labels  = (const int*)d_in[1];
    float* out         = (float*)d_out;

    char* ws = (char*)d_ws;
    unsigned short* Ebf = (unsigned short*)ws;                 // 4 MB
    float* pos_sum = (float*)(ws + (size_t)N * D * 2);         // 16 KB
    float* neg_sum = pos_sum + N;                              // 16 KB

    convert_bf16_kernel<<<(N * D / 4) / 256, 256, 0, stream>>>(
        (const float4*)emb, (ushort4*)Ebf, pos_sum);

    ms_loss_gemm<<<(32 * 33) / 2, 256, 0, stream>>>(Ebf, labels, pos_sum, neg_sum);

    finalize_kernel<<<1, 1024, 0, stream>>>(
        (const float4*)pos_sum, (const float4*)neg_sum, out);
}